// Round 12
// baseline (1640.728 us; speedup 1.0000x reference)
//
#include <hip/hip_runtime.h>
#include <hip/hip_bf16.h>

#define NN   16384
#define EE   65536
#define GG   64
#define INF  63
#define HID  2048
#define MID  1024
#define NCLS 18
#define EPS  1e-5f
#define SLOPE 0.01f
#define MR   (NN / 128)   // 128 block-rows for BN partials

typedef unsigned short ushort;
typedef unsigned int uint;

using bf16x8 = __attribute__((ext_vector_type(8))) __bf16;
using f32x4  = __attribute__((ext_vector_type(4))) float;

__device__ __forceinline__ ushort f2us(float x) {
    __hip_bfloat16 b = __float2bfloat16(x);
    return __builtin_bit_cast(ushort, b);
}
__device__ __forceinline__ float us2f(ushort u) {
    return __bfloat162float(__builtin_bit_cast(__hip_bfloat16, u));
}

// async global->LDS, 16B per lane; LDS base wave-uniform, HW adds lane*16
__device__ __forceinline__ void gll16(const ushort* g, ushort* l) {
    __builtin_amdgcn_global_load_lds(
        (const __attribute__((address_space(1))) uint*)g,
        (__attribute__((address_space(3))) uint*)l, 16, 0, 0);
}

// ---------------- utility ----------------

__global__ void k_zero_i(int* __restrict__ p, int n) {
    int i = blockIdx.x * blockDim.x + threadIdx.x;
    if (i < n) p[i] = 0;
}

// ---------------- CSR build (by dst) ----------------

__global__ void k_count(const int* __restrict__ dst, int* __restrict__ cnt) {
    int e = blockIdx.x * blockDim.x + threadIdx.x;
    if (e < EE) atomicAdd(&cnt[dst[e]], 1);
}

__global__ void k_scan(const int* __restrict__ cnt, int* __restrict__ off,
                       float* __restrict__ deg) {
    __shared__ int sh[1024];
    int t = threadIdx.x;
    int base = t * 16;
    int loc[16];
    int s = 0;
#pragma unroll
    for (int i = 0; i < 16; ++i) {
        int c = cnt[base + i];
        loc[i] = s;
        s += c;
        deg[base + i] = (float)c;
    }
    sh[t] = s;
    __syncthreads();
    for (int d = 1; d < 1024; d <<= 1) {
        int v = (t >= d) ? sh[t - d] : 0;
        __syncthreads();
        sh[t] += v;
        __syncthreads();
    }
    int excl = sh[t] - s;
#pragma unroll
    for (int i = 0; i < 16; ++i) off[base + i] = excl + loc[i];
    if (t == 1023) off[NN] = sh[1023];
}

__global__ void k_fill(const int* __restrict__ src, const int* __restrict__ dst,
                       const int* __restrict__ off, int* __restrict__ cur,
                       int* __restrict__ csr_src) {
    int e = blockIdx.x * blockDim.x + threadIdx.x;
    if (e < EE) {
        int d = dst[e];
        int p = atomicAdd(&cur[d], 1);
        csr_src[off[d] + p] = src[e];
    }
}

// ---------------- layer-1 prep (into concat [NN,128]) ----------------

__global__ void k_h2bf_c(const float* __restrict__ h, ushort* __restrict__ Xc) {
    int i = blockIdx.x * 256 + threadIdx.x;  // over NN*64
    int r = i >> 6, c = i & 63;
    Xc[(size_t)r * 128 + c] = (c < INF) ? f2us(h[(size_t)r * INF + c]) : (ushort)0;
}

__global__ void k_agg_small_c(const float* __restrict__ X, ushort* __restrict__ Xc,
                              const int* __restrict__ off, const int* __restrict__ csr_src,
                              const float* __restrict__ deg) {
    int v = blockIdx.x;
    int f = threadIdx.x;  // 64
    float acc = 0.f;
    if (f < INF) {
        int s = off[v], e = off[v + 1];
        for (int i = s; i < e; ++i) acc += X[(size_t)csr_src[i] * INF + f];
        acc /= fmaxf(deg[v], 1.f);
    }
    Xc[(size_t)v * 128 + 64 + f] = f2us(acc);
}

// ---------------- fused BN-apply + aggregation ----------------
// X[v]    = bf16(lrelu(sc*Ybf[v]+sh))
// AggX[v] = bf16(mean_nb lrelu(sc*Ybf[u]+sh))  (fp32 accum)

__global__ void k_aggbn(const ushort* __restrict__ Ybf,
                        const float* __restrict__ sc8, const float* __restrict__ sh8,
                        ushort* __restrict__ X, ushort* __restrict__ AggX,
                        const int* __restrict__ off, const int* __restrict__ csr_src,
                        const float* __restrict__ deg) {
    int v = blockIdx.x;
    int t = threadIdx.x;
    int c = t * 8;
    float sc[8], sh[8];
    *(float4*)&sc[0] = *(const float4*)&sc8[c];
    *(float4*)&sc[4] = *(const float4*)&sc8[c + 4];
    *(float4*)&sh[0] = *(const float4*)&sh8[c];
    *(float4*)&sh[4] = *(const float4*)&sh8[c + 4];

    // own row
    {
        uint4 u = ((const uint4*)(Ybf + (size_t)v * HID))[t];
        uint wds[4] = {u.x, u.y, u.z, u.w};
        uint o[4];
#pragma unroll
        for (int j = 0; j < 4; ++j) {
            float a = sc[2 * j] * us2f((ushort)(wds[j] & 0xffffu)) + sh[2 * j];
            float b = sc[2 * j + 1] * us2f((ushort)(wds[j] >> 16)) + sh[2 * j + 1];
            a = a > 0.f ? a : SLOPE * a;
            b = b > 0.f ? b : SLOPE * b;
            o[j] = (uint)f2us(a) | ((uint)f2us(b) << 16);
        }
        ((uint4*)(X + (size_t)v * HID))[t] = make_uint4(o[0], o[1], o[2], o[3]);
    }

    // neighbor mean
    int s = off[v], e = off[v + 1];
    float acc[8];
#pragma unroll
    for (int j = 0; j < 8; ++j) acc[j] = 0.f;
    for (int i = s; i < e; ++i) {
        uint4 u = ((const uint4*)(Ybf + (size_t)csr_src[i] * HID))[t];
        uint wds[4] = {u.x, u.y, u.z, u.w};
#pragma unroll
        for (int j = 0; j < 4; ++j) {
            float a = sc[2 * j] * us2f((ushort)(wds[j] & 0xffffu)) + sh[2 * j];
            float b = sc[2 * j + 1] * us2f((ushort)(wds[j] >> 16)) + sh[2 * j + 1];
            acc[2 * j]     += a > 0.f ? a : SLOPE * a;
            acc[2 * j + 1] += b > 0.f ? b : SLOPE * b;
        }
    }
    float inv = 1.f / fmaxf(deg[v], 1.f);
    uint o[4];
#pragma unroll
    for (int j = 0; j < 4; ++j)
        o[j] = (uint)f2us(acc[2 * j] * inv) | ((uint)f2us(acc[2 * j + 1] * inv) << 16);
    ((uint4*)(AggX + (size_t)v * HID))[t] = make_uint4(o[0], o[1], o[2], o[3]);
}

// ---------------- weight transposes ----------------

// paired: z=0: W0 -> Wt0 ; z=1: W1 -> Wt1.  Wt[n][k] = bf16(W[k][n]), pad 0.
__global__ void k_wt2(const float* __restrict__ W0, const float* __restrict__ W1,
                      int K, int N, ushort* __restrict__ Wt0, ushort* __restrict__ Wt1,
                      int Kp) {
    const float* W = blockIdx.z ? W1 : W0;
    ushort* Wt = blockIdx.z ? Wt1 : Wt0;
    __shared__ float t[32][33];
    int kb = blockIdx.y * 32, nb = blockIdx.x * 32;
    int tx = threadIdx.x & 31, ty = threadIdx.x >> 5;
#pragma unroll
    for (int i = 0; i < 32; i += 8) {
        int k = kb + ty + i;
        t[ty + i][tx] = (k < K) ? W[(size_t)k * N + nb + tx] : 0.f;
    }
    __syncthreads();
#pragma unroll
    for (int i = 0; i < 32; i += 8)
        Wt[(size_t)(nb + ty + i) * Kp + kb + tx] = f2us(t[tx][ty + i]);
}

// concat pair into one [N,KP] buffer: z=0 -> k-cols [0,KP/2), z=1 -> [KP/2,KP)
__global__ void k_wt2c(const float* __restrict__ W0, const float* __restrict__ W1,
                       int Kw, int N, ushort* __restrict__ Wtc, int KP) {
    const float* W = blockIdx.z ? W1 : W0;
    const int kOff = blockIdx.z ? (KP / 2) : 0;
    __shared__ float t[32][33];
    int kb = blockIdx.y * 32, nb = blockIdx.x * 32;
    int tx = threadIdx.x & 31, ty = threadIdx.x >> 5;
#pragma unroll
    for (int i = 0; i < 32; i += 8) {
        int k = kb + ty + i;
        t[ty + i][tx] = (k < Kw) ? W[(size_t)k * N + nb + tx] : 0.f;
    }
    __syncthreads();
#pragma unroll
    for (int i = 0; i < 32; i += 8)
        Wtc[(size_t)(nb + ty + i) * KP + kOff + kb + tx] = f2us(t[tx][ty + i]);
}

// single: Wt[n][k] = bf16(W[k][n])
__global__ void k_wt(const float* __restrict__ W, int K, int N,
                     ushort* __restrict__ Wt, int Kp) {
    __shared__ float t[32][33];
    int kb = blockIdx.y * 32, nb = blockIdx.x * 32;
    int tx = threadIdx.x & 31, ty = threadIdx.x >> 5;
#pragma unroll
    for (int i = 0; i < 32; i += 8) {
        int k = kb + ty + i;
        t[ty + i][tx] = (k < K) ? W[(size_t)k * N + nb + tx] : 0.f;
    }
    __syncthreads();
#pragma unroll
    for (int i = 0; i < 32; i += 8)
        Wt[(size_t)(nb + ty + i) * Kp + kb + tx] = f2us(t[tx][ty + i]);
}

// ---------------- MFMA GEMM (BK=32, double-buffered DMA, XOR-swizzled LDS) -
// C = A1@B1t^T + A2@B2t^T + bias; A bf16 [M,K] lda, Bt bf16 [N,K] ldb.
// 128x128 tile, 256 thr (4 waves), wave = 64x64 quadrant of 4x4 mfma 16x16x32.
// Pipeline: barrier(tile k ready) -> issue DMA for tile k+1 into other 8KB
// buffer -> compute tile k. The barrier's vmcnt(0) drain thus waits on a
// prefetch that had a full compute phase to land (R9's shape exposed it).
// LDS: [row][32] k-contiguous per buffer; chunk c (4/row) of row r holds
// GLOBAL k-chunk c^(r&3); reader uses (q^(la&3)) -> conflict-free (8 bank
// groups x 8 lanes, same algebra as the R9 BK=64 pattern measured at 0).
// R10 falsified per-lane global B loads in the K-loop (2.1x regression);
// both operands stay behind the async DMA. K multiple of 32.

#define BK 32

__global__ __launch_bounds__(256)
void k_mgemm(const ushort* __restrict__ A1, int lda1, const ushort* __restrict__ B1t, int ldb1, int K1,
             const ushort* __restrict__ A2, int lda2, const ushort* __restrict__ B2t, int ldb2, int K2,
             const float* __restrict__ bias, float* __restrict__ Cf, ushort* __restrict__ Cbf,
             int ldc, int fuse_lrelu, float* __restrict__ s1p, float* __restrict__ s2p,
             size_t cStrideZ) {
    __shared__ __align__(16) ushort As[2][128 * BK];   // 2 x 8 KB
    __shared__ __align__(16) ushort Bs[2][128 * BK];   // 2 x 8 KB
    __shared__ float sb1[4][64];
    __shared__ float sb2[4][64];
    const int tid = threadIdx.x;
    const int lane = tid & 63;
    const int w = tid >> 6;
    const int rowBase = blockIdx.y * 128;
    const int colBase = blockIdx.x * 128;
    const int m0 = (w & 1) * 64;
    const int n0 = (w >> 1) * 64;
    const int z = blockIdx.z;
    A1 += (size_t)z * K1;       // k-offset within row (lda spans full K)
    B1t += (size_t)z * K1;
    if (Cf) Cf += (size_t)z * cStrideZ;

    f32x4 acc[4][4];
#pragma unroll
    for (int mi = 0; mi < 4; ++mi)
#pragma unroll
        for (int ni = 0; ni < 4; ++ni) acc[mi][ni] = (f32x4){0.f, 0.f, 0.f, 0.f};

    // staging: 512 chunks (16B) per matrix per tile = 128 rows x 4 chunks.
    // thread (w,lane), j=0..1: chunk idx = j*256 + w*64 + lane ->
    //   row = j*64 + w*16 + (lane>>2), lds chunk = lane&3,
    //   global k-chunk = (lane&3) ^ (row&3) = (lane&3) ^ ((lane>>2)&3)
    const int lrowOff = w * 16 + (lane >> 2);
    const int gc8 = (((lane & 3) ^ ((lane >> 2) & 3))) * 8;   // elem offset
    const int la = lane & 15, q = lane >> 4;
    const int lq8 = (q ^ (la & 3)) * 8;                        // reader chunk

    // pass table (uniform control flow)
    const ushort* aP[2];
    const ushort* bP[2];
    size_t stA[2], stB[2];
    int tiles[2];
    int np = 0;
    if (A1 != nullptr) {
        aP[np] = A1 + (size_t)(rowBase + lrowOff) * lda1 + gc8;
        bP[np] = B1t + (size_t)(colBase + lrowOff) * ldb1 + gc8;
        stA[np] = (size_t)64 * lda1; stB[np] = (size_t)64 * ldb1;
        tiles[np] = K1 / BK; ++np;
    }
    if (A2 != nullptr) {
        aP[np] = A2 + (size_t)(rowBase + lrowOff) * lda2 + gc8;
        bP[np] = B2t + (size_t)(colBase + lrowOff) * ldb2 + gc8;
        stA[np] = (size_t)64 * lda2; stB[np] = (size_t)64 * ldb2;
        tiles[np] = K2 / BK; ++np;
    }

    auto issue = [&](int p, int t, int buf) {
        const ushort* ga = aP[p] + (size_t)t * BK;
        const ushort* gb = bP[p] + (size_t)t * BK;
        ushort* ldA = &As[buf][w * 512];
        ushort* ldB = &Bs[buf][w * 512];
        gll16(ga, ldA);
        gll16(ga + stA[p], ldA + 2048);
        gll16(gb, ldB);
        gll16(gb + stB[p], ldB + 2048);
    };

    int tot = 0;
    for (int i = 0; i < np; ++i) tot += tiles[i];

    int p = 0, t = 0, buf = 0;
    if (np > 0) issue(0, 0, 0);
    for (int it = 0; it < tot; ++it) {
        __syncthreads();                 // tile (p,t) resident in As/Bs[buf]
        int pn = p, tn = t + 1;
        if (tn == tiles[p]) { pn = p + 1; tn = 0; }
        if (pn < np) issue(pn, tn, buf ^ 1);   // DMA overlaps compute below
        const ushort* as = &As[buf][0];
        const ushort* bs = &Bs[buf][0];
        bf16x8 av[4], bv[4];
#pragma unroll
        for (int mi = 0; mi < 4; ++mi)
            av[mi] = *(const bf16x8*)&as[(m0 + mi * 16 + la) * BK + lq8];
#pragma unroll
        for (int ni = 0; ni < 4; ++ni)
            bv[ni] = *(const bf16x8*)&bs[(n0 + ni * 16 + la) * BK + lq8];
#pragma unroll
        for (int mi = 0; mi < 4; ++mi)
#pragma unroll
            for (int ni = 0; ni < 4; ++ni)
                acc[mi][ni] = __builtin_amdgcn_mfma_f32_16x16x32_bf16(
                    av[mi], bv[ni], acc[mi][ni], 0, 0, 0);
        buf ^= 1; p = pn; t = tn;
    }

    // ---- C store (C/D layout: col = lane&15, row = q*4 + reg) ----
#pragma unroll
    for (int mi = 0; mi < 4; ++mi) {
#pragma unroll
        for (int ni = 0; ni < 4; ++ni) {
            const int lc = colBase + n0 + ni * 16 + la;
            const float bv = bias ? bias[lc] : 0.f;
#pragma unroll
            for (int r = 0; r < 4; ++r) {
                const int row = rowBase + m0 + mi * 16 + q * 4 + r;
                float v = acc[mi][ni][r] + bv;
                if (fuse_lrelu) v = v > 0.f ? v : SLOPE * v;
                if (Cbf) Cbf[(size_t)row * ldc + lc] = f2us(v);
                else     Cf[(size_t)row * ldc + lc] = v;
            }
        }
    }

    // ---- fused BN partial stats (pre-activation, fp32 exact) ----
    if (s1p) {
#pragma unroll
        for (int ni = 0; ni < 4; ++ni) {
            const int lc = colBase + n0 + ni * 16 + la;
            const float bv = bias ? bias[lc] : 0.f;
            float t1 = 0.f, t2 = 0.f;
#pragma unroll
            for (int mi = 0; mi < 4; ++mi)
#pragma unroll
                for (int r = 0; r < 4; ++r) {
                    float v = acc[mi][ni][r] + bv;
                    t1 += v;
                    t2 += v * v;
                }
            t1 += __shfl_xor(t1, 16);
            t1 += __shfl_xor(t1, 32);
            t2 += __shfl_xor(t2, 16);
            t2 += __shfl_xor(t2, 32);
            if (q == 0) {
                sb1[w][ni * 16 + la] = t1;
                sb2[w][ni * 16 + la] = t2;
            }
        }
        __syncthreads();
        if (tid < 128) {
            int half = tid >> 6, j = tid & 63;
            float v1 = sb1[2 * half][j] + sb1[2 * half + 1][j];
            float v2 = sb2[2 * half][j] + sb2[2 * half + 1][j];
            size_t o = (size_t)blockIdx.y * ldc + colBase + half * 64 + j;
            s1p[o] = v1;
            s2p[o] = v2;
        }
    }
}

// ---------------- BatchNorm finalize ----------------

__global__ void k_bn_finalize(const float* __restrict__ p1, const float* __restrict__ p2,
                              const float* __restrict__ gamma, const float* __restrict__ beta,
                              float* __restrict__ scale, float* __restrict__ shift) {
    int c = blockIdx.x * 256 + threadIdx.x;
    if (c >= HID) return;
    float s1 = 0.f, s2 = 0.f;
    for (int rb = 0; rb < MR; ++rb) {
        s1 += p1[(size_t)rb * HID + c];
        s2 += p2[(size_t)rb * HID + c];
    }
    float mean = s1 * (1.f / (float)NN);
    float var = s2 * (1.f / (float)NN) - mean * mean;
    var = fmaxf(var, 0.f);
    float sc = gamma[c] * rsqrtf(var + EPS);
    scale[c] = sc;
    shift[c] = beta[c] - mean * sc;
}

// ---------------- fused BN + pooling ----------------

__global__ void k_poolbn(const ushort* __restrict__ Ybf,
                         const float* __restrict__ scale, const float* __restrict__ shift,
                         const int* __restrict__ gstart, ushort* __restrict__ hgbf) {
    int g = blockIdx.y;
    int col = blockIdx.x * 256 + threadIdx.x;
    if (g >= GG) {
        hgbf[(size_t)g * HID + col] = 0;
        return;
    }
    int s = gstart[g], e = gstart[g + 1];
    float sc = scale[col], sh = shift[col];
    float acc = 0.f;
    for (int n = s; n < e; ++n) {
        float v = sc * us2f(Ybf[(size_t)n * HID + col]) + sh;
        acc += v > 0.f ? v : SLOPE * v;
    }
    hgbf[(size_t)g * HID + col] = f2us(acc / fmaxf((float)(e - s), 1.f));
}

__global__ void k_gstart(const int* __restrict__ gid, int* __restrict__ gstart) {
    int g = threadIdx.x;
    if (g > GG) return;
    int lo = 0, hi = NN;
    while (lo < hi) {
        int mid = (lo + hi) >> 1;
        if (gid[mid] < g) lo = mid + 1; else hi = mid;
    }
    gstart[g] = lo;
}

// ---------------- split-K reduce for head GEMMs ----------------

__global__ void k_redhead(const float* __restrict__ part, int P, size_t strideZ,
                          const float* __restrict__ bias, int ldc,
                          ushort* __restrict__ obf, float* __restrict__ of, int n) {
    int i = blockIdx.x * 256 + threadIdx.x;
    if (i >= n) return;
    float s = 0.f;
    for (int p = 0; p < P; ++p) s += part[(size_t)p * strideZ + i];
    s += bias[i % ldc];
    s = s > 0.f ? s : SLOPE * s;
    if (obf) obf[i] = f2us(s);
    else     of[i] = s;
}

__global__ void k_fc3(const float* __restrict__ x2, const float* __restrict__ W,
                      const float* __restrict__ b, float* __restrict__ out) {
    int g = blockIdx.x;
    int tid = threadIdx.x;
    float part[NCLS];
#pragma unroll
    for (int c = 0; c < NCLS; ++c) part[c] = 0.f;
    for (int k = tid; k < MID; k += 256) {
        float x = x2[(size_t)g * MID + k];
        const float* wr = W + (size_t)k * NCLS;
#pragma unroll
        for (int c = 0; c < NCLS; ++c) part[c] += x * wr[c];
    }
    __shared__ float red[4][NCLS];
    int lane = tid & 63, w = tid >> 6;
#pragma unroll
    for (int c = 0; c < NCLS; ++c) {
        float v = part[c];
        for (int o = 32; o > 0; o >>= 1) v += __shfl_down(v, o, 64);
        if (lane == 0) red[w][c] = v;
    }
    __syncthreads();
    if (tid < NCLS)
        out[(size_t)g * NCLS + tid] = red[0][tid] + red[1][tid] + red[2][tid] + red[3][tid] + b[tid];
}

// ---------------- launcher ----------------

extern "C" void kernel_launch(void* const* d_in, const int* in_sizes, int n_in,
                              void* d_out, int out_size, void* d_ws, size_t ws_size,
                              hipStream_t stream) {
    const float* h        = (const float*)d_in[0];
    const int*   src      = (const int*)d_in[1];
    const int*   dst      = (const int*)d_in[2];
    const int*   graph_id = (const int*)d_in[3];
    const float* Ws1 = (const float*)d_in[4];
    const float* Wn1 = (const float*)d_in[5];
    const float* b1  = (const float*)d_in[6];
    const float* Ws2 = (const float*)d_in[7];
    const float* Wn2 = (const float*)d_in[8];
    const float* b2  = (const float*)d_in[9];
    const float* Ws3 = (const float*)d_in[10];
    const float* Wn3 = (const float*)d_in[11];
    const float* b3  = (const float*)d_in[12];
    const float* g1  = (const float*)d_in[13];
    const float* be1 = (const float*)d_in[14];
    const float* g2  = (const float*)d_in[15];
    const float* be2 = (const float*)d_in[16];
    const float* g3  = (const float*)d_in[17];
    const float* be3 = (const float*)d_in[18];
    const float* fc1_w = (const float*)d_in[19];
    const float* fc1_b = (const float*)d_in[20];
    const float* fc2_w = (const float*)d_in[21];
    const float* fc2_b = (const float*)d_in[22];
    const float* fc3_w = (const float*)d_in[23];
    const float* fc3_b = (const float*)d_in[24];
    float* out = (float*)d_out;

    size_t off_b = 0;
    auto alloc = [&](size_t bytes) -> void* {
        void* p = (char*)d_ws + off_b;
        off_b += (bytes + 255) & ~(size_t)255;
        return p;
    };
    ushort* Wt0    = (ushort*)alloc((size_t)2 * HID * HID * 2);  // 16 MiB (2 slots)
    ushort* Wt1    = Wt0 + (size_t)HID * HID;
    ushort* X      = (ushort*)alloc((size_t)NN * HID * 2);       // 64 MiB
    ushort* AggX   = (ushort*)alloc((size_t)NN * HID * 2);       // 64 MiB
    ushort* Ybf    = (ushort*)alloc((size_t)NN * HID * 2);       // 64 MiB
    float*  deg    = (float*)alloc((size_t)NN * 4);
    int*    csroff = (int*)alloc((size_t)(NN + 1) * 4);
    int*    cursor = (int*)alloc((size_t)NN * 4);
    int*    csrsrc = (int*)alloc((size_t)EE * 4);
    float*  p1     = (float*)alloc((size_t)MR * HID * 4);        // 1 MiB
    float*  p2     = (float*)alloc((size_t)MR * HID * 4);        // 1 MiB
    float*  bnsc   = (float*)alloc((size_t)HID * 4);
    float*  bnsh   = (float*)alloc((size_t)HID * 4);
    int*    gstart = (int*)alloc((size_t)(GG + 1) * 4);
    // total ~212 MiB

    // layer-1 concat input [NN,128] in X region (dead before aggbn writes X)
    ushort* Xc128 = X;
    // head scratch in AggX region (dead after layer-3 GEMM; Ybf live till poolbn)
    ushort* hgbf  = AggX;                                     // [128,2048] bf16
    ushort* x1bf  = AggX + (size_t)128 * HID;                 // [128,2048] bf16
    float*  x2f   = (float*)(AggX + (size_t)2 * 128 * HID);   // [128,1024] fp32
    float*  partF = (float*)(AggX + (size_t)3 * 128 * HID);   // 4 MiB fp32 partials

    // ---- CSR build ----
    k_zero_i<<<dim3(NN / 256), dim3(256), 0, stream>>>(cursor, NN);
    k_count<<<dim3(EE / 256), dim3(256), 0, stream>>>(dst, cursor);
    k_scan<<<dim3(1), dim3(1024), 0, stream>>>(cursor, csroff, deg);
    k_zero_i<<<dim3(NN / 256), dim3(256), 0, stream>>>(cursor, NN);
    k_fill<<<dim3(EE / 256), dim3(256), 0, stream>>>(src, dst, csroff, cursor, csrsrc);
    k_gstart<<<dim3(1), dim3(128), 0, stream>>>(graph_id, gstart);

    // ---- layer 1: concat input K=128, single pass ----
    k_h2bf_c<<<dim3(NN * 64 / 256), dim3(256), 0, stream>>>(h, Xc128);
    k_agg_small_c<<<dim3(NN), dim3(64), 0, stream>>>(h, Xc128, csroff, csrsrc, deg);
    k_wt2c<<<dim3(HID / 32, 2, 2), dim3(256), 0, stream>>>(Ws1, Wn1, INF, HID, Wt0, 128);
    k_mgemm<<<dim3(HID / 128, NN / 128, 1), dim3(256), 0, stream>>>(
        Xc128, 128, Wt0, 128, 128,
        (const ushort*)nullptr, 0, (const ushort*)nullptr, 0, 0,
        b1, (float*)nullptr, Ybf, HID, 0, p1, p2, 0);
    k_bn_finalize<<<dim3(HID / 256), dim3(256), 0, stream>>>(p1, p2, g1, be1, bnsc, bnsh);
    k_aggbn<<<dim3(NN), dim3(256), 0, stream>>>(Ybf, bnsc, bnsh, X, AggX, csroff, csrsrc, deg);

    // ---- layer 2: two-pass K=2048+2048 ----
    k_wt2<<<dim3(HID / 32, HID / 32, 2), dim3(256), 0, stream>>>(Ws2, Wn2, HID, HID, Wt0, Wt1, HID);
    k_mgemm<<<dim3(HID / 128, NN / 128, 1), dim3(256), 0, stream>>>(
        X, HID, Wt0, HID, HID,
        AggX, HID, Wt1, HID, HID,
        b2, (float*)nullptr, Ybf, HID, 0, p1, p2, 0);
    k_bn_finalize<<<dim3(HID / 256), dim3(256), 0, stream>>>(p1, p2, g2, be2, bnsc, bnsh);
    k_aggbn<<<dim3(NN), dim3(256), 0, stream>>>(Ybf, bnsc, bnsh, X, AggX, csroff, csrsrc, deg);

    // ---- layer 3 ----
    k_wt2<<<dim3(HID / 32, HID / 32, 2), dim3(256), 0, stream>>>(Ws3, Wn3, HID, HID, Wt0, Wt1, HID);
    k_mgemm<<<dim3(HID / 128, NN / 128, 1), dim3(256), 0, stream>>>(
        X, HID, Wt0, HID, HID,
        AggX, HID, Wt1, HID, HID,
        b3, (float*)nullptr, Ybf, HID, 0, p1, p2, 0);
    k_bn_finalize<<<dim3(HID / 256), dim3(256), 0, stream>>>(p1, p2, g3, be3, bnsc, bnsh);

    // ---- fused BN + pooling (Ybf -> padded bf16 hg; AggX region now scratch) ----
    k_poolbn<<<dim3(HID / 256, 128), dim3(256), 0, stream>>>(Ybf, bnsc, bnsh, gstart, hgbf);

    // ---- MLP head (split-K x4, deterministic two-stage) ----
    k_wt<<<dim3(HID / 32, HID / 32), dim3(256), 0, stream>>>(fc1_w, HID, HID, Wt0, HID);
    k_wt<<<dim3(MID / 32, HID / 32), dim3(256), 0, stream>>>(fc2_w, HID, MID, Wt1, HID);
    k_mgemm<<<dim3(HID / 128, 1, 4), dim3(256), 0, stream>>>(
        hgbf, HID, Wt0, HID, HID / 4,
        (const ushort*)nullptr, 0, (const ushort*)nullptr, 0, 0,
        (const float*)nullptr, partF, (ushort*)nullptr, HID, 0,
        (float*)nullptr, (float*)nullptr, (size_t)128 * HID);
    k_redhead<<<dim3(128 * HID / 256), dim3(256), 0, stream>>>(
        partF, 4, (size_t)128 * HID, fc1_b, HID, x1bf, (float*)nullptr, 128 * HID);
    k_mgemm<<<dim3(MID / 128, 1, 4), dim3(256), 0, stream>>>(
        x1bf, HID, Wt1, HID, HID / 4,
        (const ushort*)nullptr, 0, (const ushort*)nullptr, 0, 0,
        (const float*)nullptr, partF, (ushort*)nullptr, MID, 0,
        (float*)nullptr, (float*)nullptr, (size_t)128 * MID);
    k_redhead<<<dim3(128 * MID / 256), dim3(256), 0, stream>>>(
        partF, 4, (size_t)128 * MID, fc2_b, MID, (ushort*)nullptr, x2f, 128 * MID);
    k_fc3<<<dim3(GG), dim3(256), 0, stream>>>(x2f, fc3_w, fc3_b, out);
}

// Round 13
// 1087.959 us; speedup vs baseline: 1.5081x; 1.5081x over previous
//
#include <hip/hip_runtime.h>
#include <hip/hip_bf16.h>

#define NN   16384
#define EE   65536
#define GG   64
#define INF  63
#define HID  2048
#define MID  1024
#define NCLS 18
#define EPS  1e-5f
#define SLOPE 0.01f
#define MR   (NN / 128)   // 128 block-rows for BN partials

typedef unsigned short ushort;
typedef unsigned int uint;

using bf16x8 = __attribute__((ext_vector_type(8))) __bf16;
using f32x4  = __attribute__((ext_vector_type(4))) float;

__device__ __forceinline__ ushort f2us(float x) {
    __hip_bfloat16 b = __float2bfloat16(x);
    return __builtin_bit_cast(ushort, b);
}
__device__ __forceinline__ float us2f(ushort u) {
    return __bfloat162float(__builtin_bit_cast(__hip_bfloat16, u));
}

// async global->LDS, 16B per lane; LDS base wave-uniform, HW adds lane*16
__device__ __forceinline__ void gll16(const ushort* g, ushort* l) {
    __builtin_amdgcn_global_load_lds(
        (const __attribute__((address_space(1))) uint*)g,
        (__attribute__((address_space(3))) uint*)l, 16, 0, 0);
}

// ---------------- utility ----------------

__global__ void k_zero_i(int* __restrict__ p, int n) {
    int i = blockIdx.x * blockDim.x + threadIdx.x;
    if (i < n) p[i] = 0;
}

// ---------------- CSR build (by dst) ----------------

__global__ void k_count(const int* __restrict__ dst, int* __restrict__ cnt) {
    int e = blockIdx.x * blockDim.x + threadIdx.x;
    if (e < EE) atomicAdd(&cnt[dst[e]], 1);
}

__global__ void k_scan(const int* __restrict__ cnt, int* __restrict__ off,
                       float* __restrict__ deg) {
    __shared__ int sh[1024];
    int t = threadIdx.x;
    int base = t * 16;
    int loc[16];
    int s = 0;
#pragma unroll
    for (int i = 0; i < 16; ++i) {
        int c = cnt[base + i];
        loc[i] = s;
        s += c;
        deg[base + i] = (float)c;
    }
    sh[t] = s;
    __syncthreads();
    for (int d = 1; d < 1024; d <<= 1) {
        int v = (t >= d) ? sh[t - d] : 0;
        __syncthreads();
        sh[t] += v;
        __syncthreads();
    }
    int excl = sh[t] - s;
#pragma unroll
    for (int i = 0; i < 16; ++i) off[base + i] = excl + loc[i];
    if (t == 1023) off[NN] = sh[1023];
}

__global__ void k_fill(const int* __restrict__ src, const int* __restrict__ dst,
                       const int* __restrict__ off, int* __restrict__ cur,
                       int* __restrict__ csr_src) {
    int e = blockIdx.x * blockDim.x + threadIdx.x;
    if (e < EE) {
        int d = dst[e];
        int p = atomicAdd(&cur[d], 1);
        csr_src[off[d] + p] = src[e];
    }
}

// ---------------- layer-1 prep (into concat [NN,128]) ----------------

__global__ void k_h2bf_c(const float* __restrict__ h, ushort* __restrict__ Xc) {
    int i = blockIdx.x * 256 + threadIdx.x;  // over NN*64
    int r = i >> 6, c = i & 63;
    Xc[(size_t)r * 128 + c] = (c < INF) ? f2us(h[(size_t)r * INF + c]) : (ushort)0;
}

__global__ void k_agg_small_c(const float* __restrict__ X, ushort* __restrict__ Xc,
                              const int* __restrict__ off, const int* __restrict__ csr_src,
                              const float* __restrict__ deg) {
    int v = blockIdx.x;
    int f = threadIdx.x;  // 64
    float acc = 0.f;
    if (f < INF) {
        int s = off[v], e = off[v + 1];
        for (int i = s; i < e; ++i) acc += X[(size_t)csr_src[i] * INF + f];
        acc /= fmaxf(deg[v], 1.f);
    }
    Xc[(size_t)v * 128 + 64 + f] = f2us(acc);
}

// ---------------- fused BN-apply + aggregation ----------------
// X[v]    = bf16(lrelu(sc*Ybf[v]+sh))
// AggX[v] = bf16(mean_nb lrelu(sc*Ybf[u]+sh))  (fp32 accum)

__global__ void k_aggbn(const ushort* __restrict__ Ybf,
                        const float* __restrict__ sc8, const float* __restrict__ sh8,
                        ushort* __restrict__ X, ushort* __restrict__ AggX,
                        const int* __restrict__ off, const int* __restrict__ csr_src,
                        const float* __restrict__ deg) {
    int v = blockIdx.x;
    int t = threadIdx.x;
    int c = t * 8;
    float sc[8], sh[8];
    *(float4*)&sc[0] = *(const float4*)&sc8[c];
    *(float4*)&sc[4] = *(const float4*)&sc8[c + 4];
    *(float4*)&sh[0] = *(const float4*)&sh8[c];
    *(float4*)&sh[4] = *(const float4*)&sh8[c + 4];

    // own row
    {
        uint4 u = ((const uint4*)(Ybf + (size_t)v * HID))[t];
        uint wds[4] = {u.x, u.y, u.z, u.w};
        uint o[4];
#pragma unroll
        for (int j = 0; j < 4; ++j) {
            float a = sc[2 * j] * us2f((ushort)(wds[j] & 0xffffu)) + sh[2 * j];
            float b = sc[2 * j + 1] * us2f((ushort)(wds[j] >> 16)) + sh[2 * j + 1];
            a = a > 0.f ? a : SLOPE * a;
            b = b > 0.f ? b : SLOPE * b;
            o[j] = (uint)f2us(a) | ((uint)f2us(b) << 16);
        }
        ((uint4*)(X + (size_t)v * HID))[t] = make_uint4(o[0], o[1], o[2], o[3]);
    }

    // neighbor mean
    int s = off[v], e = off[v + 1];
    float acc[8];
#pragma unroll
    for (int j = 0; j < 8; ++j) acc[j] = 0.f;
    for (int i = s; i < e; ++i) {
        uint4 u = ((const uint4*)(Ybf + (size_t)csr_src[i] * HID))[t];
        uint wds[4] = {u.x, u.y, u.z, u.w};
#pragma unroll
        for (int j = 0; j < 4; ++j) {
            float a = sc[2 * j] * us2f((ushort)(wds[j] & 0xffffu)) + sh[2 * j];
            float b = sc[2 * j + 1] * us2f((ushort)(wds[j] >> 16)) + sh[2 * j + 1];
            acc[2 * j]     += a > 0.f ? a : SLOPE * a;
            acc[2 * j + 1] += b > 0.f ? b : SLOPE * b;
        }
    }
    float inv = 1.f / fmaxf(deg[v], 1.f);
    uint o[4];
#pragma unroll
    for (int j = 0; j < 4; ++j)
        o[j] = (uint)f2us(acc[2 * j] * inv) | ((uint)f2us(acc[2 * j + 1] * inv) << 16);
    ((uint4*)(AggX + (size_t)v * HID))[t] = make_uint4(o[0], o[1], o[2], o[3]);
}

// ---------------- weight transposes ----------------

// paired: z=0: W0 -> Wt0 ; z=1: W1 -> Wt1.  Wt[n][k] = bf16(W[k][n]), pad 0.
__global__ void k_wt2(const float* __restrict__ W0, const float* __restrict__ W1,
                      int K, int N, ushort* __restrict__ Wt0, ushort* __restrict__ Wt1,
                      int Kp) {
    const float* W = blockIdx.z ? W1 : W0;
    ushort* Wt = blockIdx.z ? Wt1 : Wt0;
    __shared__ float t[32][33];
    int kb = blockIdx.y * 32, nb = blockIdx.x * 32;
    int tx = threadIdx.x & 31, ty = threadIdx.x >> 5;
#pragma unroll
    for (int i = 0; i < 32; i += 8) {
        int k = kb + ty + i;
        t[ty + i][tx] = (k < K) ? W[(size_t)k * N + nb + tx] : 0.f;
    }
    __syncthreads();
#pragma unroll
    for (int i = 0; i < 32; i += 8)
        Wt[(size_t)(nb + ty + i) * Kp + kb + tx] = f2us(t[tx][ty + i]);
}

// concat pair into one [N,KP] buffer: z=0 -> k-cols [0,KP/2), z=1 -> [KP/2,KP)
__global__ void k_wt2c(const float* __restrict__ W0, const float* __restrict__ W1,
                       int Kw, int N, ushort* __restrict__ Wtc, int KP) {
    const float* W = blockIdx.z ? W1 : W0;
    const int kOff = blockIdx.z ? (KP / 2) : 0;
    __shared__ float t[32][33];
    int kb = blockIdx.y * 32, nb = blockIdx.x * 32;
    int tx = threadIdx.x & 31, ty = threadIdx.x >> 5;
#pragma unroll
    for (int i = 0; i < 32; i += 8) {
        int k = kb + ty + i;
        t[ty + i][tx] = (k < Kw) ? W[(size_t)k * N + nb + tx] : 0.f;
    }
    __syncthreads();
#pragma unroll
    for (int i = 0; i < 32; i += 8)
        Wtc[(size_t)(nb + ty + i) * KP + kOff + kb + tx] = f2us(t[tx][ty + i]);
}

// single: Wt[n][k] = bf16(W[k][n])
__global__ void k_wt(const float* __restrict__ W, int K, int N,
                     ushort* __restrict__ Wt, int Kp) {
    __shared__ float t[32][33];
    int kb = blockIdx.y * 32, nb = blockIdx.x * 32;
    int tx = threadIdx.x & 31, ty = threadIdx.x >> 5;
#pragma unroll
    for (int i = 0; i < 32; i += 8) {
        int k = kb + ty + i;
        t[ty + i][tx] = (k < K) ? W[(size_t)k * N + nb + tx] : 0.f;
    }
    __syncthreads();
#pragma unroll
    for (int i = 0; i < 32; i += 8)
        Wt[(size_t)(nb + ty + i) * Kp + kb + tx] = f2us(t[tx][ty + i]);
}

// ---------------- MFMA GEMM (two-pass, BK=64, XOR-swizzled LDS) ------------
// R9-proven kernel (992 TF, 0 bank conflicts). C = A1@B1t^T + A2@B2t^T + bias;
// A bf16 [M,K] lda, Bt bf16 [N,K] ldb. 128x128 tile, BK=64 (32 MFMA/barrier),
// 256 thr (4 waves), wave = 64x64 quadrant of 4x4 mfma 16x16x32.
// LDS: [row][64] k-contiguous, chunk c8 of row r holds GLOBAL k-chunk
// (c8 ^ (r&7)); reader uses ((kk*4+q) ^ (la&7)) -> 2-way aliasing = free.
// NOTE the bank spread comes from the 8 chunks/row (c8*16B covers all 32
// banks); 4 chunks/row (BK=32, R12) only spans 8 bank-quads -> conflicts.
// R10 falsified per-lane global B loads in the K-loop (2.1x regression);
// R12 falsified BK=32 dbuf (scratch-spilled pass table + broken swizzle).
// Both operands stay behind the async global_load_lds DMA.
// Split-K via blockIdx.z (single-pass callers only). K multiple of 64.

#define BK 64

__global__ __launch_bounds__(256)
void k_mgemm(const ushort* __restrict__ A1, int lda1, const ushort* __restrict__ B1t, int ldb1, int K1,
             const ushort* __restrict__ A2, int lda2, const ushort* __restrict__ B2t, int ldb2, int K2,
             const float* __restrict__ bias, float* __restrict__ Cf, ushort* __restrict__ Cbf,
             int ldc, int fuse_lrelu, float* __restrict__ s1p, float* __restrict__ s2p,
             size_t cStrideZ) {
    __shared__ __align__(16) ushort As[128 * BK];
    __shared__ __align__(16) ushort Bs[128 * BK];
    __shared__ float sb1[4][64];
    __shared__ float sb2[4][64];
    const int tid = threadIdx.x;
    const int lane = tid & 63;
    const int w = tid >> 6;
    const int rowBase = blockIdx.y * 128;
    const int colBase = blockIdx.x * 128;
    const int m0 = (w & 1) * 64;
    const int n0 = (w >> 1) * 64;
    const int z = blockIdx.z;
    A1 += (size_t)z * K1;       // k-offset within row (lda spans full K)
    B1t += (size_t)z * K1;
    if (Cf) Cf += (size_t)z * cStrideZ;

    f32x4 acc[4][4];
#pragma unroll
    for (int mi = 0; mi < 4; ++mi)
#pragma unroll
        for (int ni = 0; ni < 4; ++ni) acc[mi][ni] = (f32x4){0.f, 0.f, 0.f, 0.f};

    // staging: 1024 chunks (16B) per matrix = 128 rows x 8 chunks.
    // thread (w,lane) does chunks j*256 + w*64 + lane, j=0..3:
    //   row = j*32 + w*8 + (lane>>3), lds c8 = lane&7,
    //   global k-chunk = (lane&7) ^ (lane>>3)   [= c8 ^ (row&7)]
    const int lrow = w * 8 + (lane >> 3);
    const int gc8 = ((lane & 7) ^ (lane >> 3)) * 8;   // element offset
    const int la = lane & 15, q = lane >> 4;
    const int la7 = lane & 7;

    for (int pass = 0; pass < 2; ++pass) {
        const ushort* A  = pass ? A2 : A1;
        const ushort* Bt = pass ? B2t : B1t;
        const int K   = pass ? K2 : K1;
        const int lda = pass ? lda2 : lda1;
        const int ldb = pass ? ldb2 : ldb1;
        if (A == nullptr) continue;
        const ushort* gA = A + (size_t)(rowBase + lrow) * lda + gc8;
        const ushort* gB = Bt + (size_t)(colBase + lrow) * ldb + gc8;
        for (int kt = 0; kt < K; kt += BK) {
#pragma unroll
            for (int j = 0; j < 4; ++j) {
                gll16(gA + (size_t)(j * 32) * lda + kt, As + j * 2048 + w * 512);
                gll16(gB + (size_t)(j * 32) * ldb + kt, Bs + j * 2048 + w * 512);
            }
            __syncthreads();
#pragma unroll
            for (int kk = 0; kk < 2; ++kk) {
                const int lc8 = ((kk * 4 + q) ^ la7) * 8;
                bf16x8 av[4], bv[4];
#pragma unroll
                for (int mi = 0; mi < 4; ++mi)
                    av[mi] = *(const bf16x8*)&As[(m0 + mi * 16 + la) * BK + lc8];
#pragma unroll
                for (int ni = 0; ni < 4; ++ni)
                    bv[ni] = *(const bf16x8*)&Bs[(n0 + ni * 16 + la) * BK + lc8];
#pragma unroll
                for (int mi = 0; mi < 4; ++mi)
#pragma unroll
                    for (int ni = 0; ni < 4; ++ni)
                        acc[mi][ni] = __builtin_amdgcn_mfma_f32_16x16x32_bf16(
                            av[mi], bv[ni], acc[mi][ni], 0, 0, 0);
            }
            __syncthreads();
        }
    }

    // ---- C store (C/D layout: col = lane&15, row = q*4 + reg) ----
#pragma unroll
    for (int mi = 0; mi < 4; ++mi) {
#pragma unroll
        for (int ni = 0; ni < 4; ++ni) {
            const int lc = colBase + n0 + ni * 16 + la;
            const float bv = bias ? bias[lc] : 0.f;
#pragma unroll
            for (int r = 0; r < 4; ++r) {
                const int row = rowBase + m0 + mi * 16 + q * 4 + r;
                float v = acc[mi][ni][r] + bv;
                if (fuse_lrelu) v = v > 0.f ? v : SLOPE * v;
                if (Cbf) Cbf[(size_t)row * ldc + lc] = f2us(v);
                else     Cf[(size_t)row * ldc + lc] = v;
            }
        }
    }

    // ---- fused BN partial stats (pre-activation, fp32 exact) ----
    if (s1p) {
#pragma unroll
        for (int ni = 0; ni < 4; ++ni) {
            const int lc = colBase + n0 + ni * 16 + la;
            const float bv = bias ? bias[lc] : 0.f;
            float t1 = 0.f, t2 = 0.f;
#pragma unroll
            for (int mi = 0; mi < 4; ++mi)
#pragma unroll
                for (int r = 0; r < 4; ++r) {
                    float v = acc[mi][ni][r] + bv;
                    t1 += v;
                    t2 += v * v;
                }
            t1 += __shfl_xor(t1, 16);
            t1 += __shfl_xor(t1, 32);
            t2 += __shfl_xor(t2, 16);
            t2 += __shfl_xor(t2, 32);
            if (q == 0) {
                sb1[w][ni * 16 + la] = t1;
                sb2[w][ni * 16 + la] = t2;
            }
        }
        __syncthreads();
        if (tid < 128) {
            int half = tid >> 6, j = tid & 63;
            float v1 = sb1[2 * half][j] + sb1[2 * half + 1][j];
            float v2 = sb2[2 * half][j] + sb2[2 * half + 1][j];
            size_t o = (size_t)blockIdx.y * ldc + colBase + half * 64 + j;
            s1p[o] = v1;
            s2p[o] = v2;
        }
    }
}

// ---------------- BatchNorm finalize ----------------

__global__ void k_bn_finalize(const float* __restrict__ p1, const float* __restrict__ p2,
                              const float* __restrict__ gamma, const float* __restrict__ beta,
                              float* __restrict__ scale, float* __restrict__ shift) {
    int c = blockIdx.x * 256 + threadIdx.x;
    if (c >= HID) return;
    float s1 = 0.f, s2 = 0.f;
    for (int rb = 0; rb < MR; ++rb) {
        s1 += p1[(size_t)rb * HID + c];
        s2 += p2[(size_t)rb * HID + c];
    }
    float mean = s1 * (1.f / (float)NN);
    float var = s2 * (1.f / (float)NN) - mean * mean;
    var = fmaxf(var, 0.f);
    float sc = gamma[c] * rsqrtf(var + EPS);
    scale[c] = sc;
    shift[c] = beta[c] - mean * sc;
}

// ---------------- fused BN + pooling ----------------

__global__ void k_poolbn(const ushort* __restrict__ Ybf,
                         const float* __restrict__ scale, const float* __restrict__ shift,
                         const int* __restrict__ gstart, ushort* __restrict__ hgbf) {
    int g = blockIdx.y;
    int col = blockIdx.x * 256 + threadIdx.x;
    if (g >= GG) {
        hgbf[(size_t)g * HID + col] = 0;
        return;
    }
    int s = gstart[g], e = gstart[g + 1];
    float sc = scale[col], sh = shift[col];
    float acc = 0.f;
    for (int n = s; n < e; ++n) {
        float v = sc * us2f(Ybf[(size_t)n * HID + col]) + sh;
        acc += v > 0.f ? v : SLOPE * v;
    }
    hgbf[(size_t)g * HID + col] = f2us(acc / fmaxf((float)(e - s), 1.f));
}

__global__ void k_gstart(const int* __restrict__ gid, int* __restrict__ gstart) {
    int g = threadIdx.x;
    if (g > GG) return;
    int lo = 0, hi = NN;
    while (lo < hi) {
        int mid = (lo + hi) >> 1;
        if (gid[mid] < g) lo = mid + 1; else hi = mid;
    }
    gstart[g] = lo;
}

// ---------------- split-K reduce for head GEMMs ----------------

__global__ void k_redhead(const float* __restrict__ part, int P, size_t strideZ,
                          const float* __restrict__ bias, int ldc,
                          ushort* __restrict__ obf, float* __restrict__ of, int n) {
    int i = blockIdx.x * 256 + threadIdx.x;
    if (i >= n) return;
    float s = 0.f;
    for (int p = 0; p < P; ++p) s += part[(size_t)p * strideZ + i];
    s += bias[i % ldc];
    s = s > 0.f ? s : SLOPE * s;
    if (obf) obf[i] = f2us(s);
    else     of[i] = s;
}

__global__ void k_fc3(const float* __restrict__ x2, const float* __restrict__ W,
                      const float* __restrict__ b, float* __restrict__ out) {
    int g = blockIdx.x;
    int tid = threadIdx.x;
    float part[NCLS];
#pragma unroll
    for (int c = 0; c < NCLS; ++c) part[c] = 0.f;
    for (int k = tid; k < MID; k += 256) {
        float x = x2[(size_t)g * MID + k];
        const float* wr = W + (size_t)k * NCLS;
#pragma unroll
        for (int c = 0; c < NCLS; ++c) part[c] += x * wr[c];
    }
    __shared__ float red[4][NCLS];
    int lane = tid & 63, w = tid >> 6;
#pragma unroll
    for (int c = 0; c < NCLS; ++c) {
        float v = part[c];
        for (int o = 32; o > 0; o >>= 1) v += __shfl_down(v, o, 64);
        if (lane == 0) red[w][c] = v;
    }
    __syncthreads();
    if (tid < NCLS)
        out[(size_t)g * NCLS + tid] = red[0][tid] + red[1][tid] + red[2][tid] + red[3][tid] + b[tid];
}

// ---------------- launcher ----------------

extern "C" void kernel_launch(void* const* d_in, const int* in_sizes, int n_in,
                              void* d_out, int out_size, void* d_ws, size_t ws_size,
                              hipStream_t stream) {
    const float* h        = (const float*)d_in[0];
    const int*   src      = (const int*)d_in[1];
    const int*   dst      = (const int*)d_in[2];
    const int*   graph_id = (const int*)d_in[3];
    const float* Ws1 = (const float*)d_in[4];
    const float* Wn1 = (const float*)d_in[5];
    const float* b1  = (const float*)d_in[6];
    const float* Ws2 = (const float*)d_in[7];
    const float* Wn2 = (const float*)d_in[8];
    const float* b2  = (const float*)d_in[9];
    const float* Ws3 = (const float*)d_in[10];
    const float* Wn3 = (const float*)d_in[11];
    const float* b3  = (const float*)d_in[12];
    const float* g1  = (const float*)d_in[13];
    const float* be1 = (const float*)d_in[14];
    const float* g2  = (const float*)d_in[15];
    const float* be2 = (const float*)d_in[16];
    const float* g3  = (const float*)d_in[17];
    const float* be3 = (const float*)d_in[18];
    const float* fc1_w = (const float*)d_in[19];
    const float* fc1_b = (const float*)d_in[20];
    const float* fc2_w = (const float*)d_in[21];
    const float* fc2_b = (const float*)d_in[22];
    const float* fc3_w = (const float*)d_in[23];
    const float* fc3_b = (const float*)d_in[24];
    float* out = (float*)d_out;

    size_t off_b = 0;
    auto alloc = [&](size_t bytes) -> void* {
        void* p = (char*)d_ws + off_b;
        off_b += (bytes + 255) & ~(size_t)255;
        return p;
    };
    ushort* Wt0    = (ushort*)alloc((size_t)2 * HID * HID * 2);  // 16 MiB (2 slots)
    ushort* Wt1    = Wt0 + (size_t)HID * HID;
    ushort* X      = (ushort*)alloc((size_t)NN * HID * 2);       // 64 MiB
    ushort* AggX   = (ushort*)alloc((size_t)NN * HID * 2);       // 64 MiB
    ushort* Ybf    = (ushort*)alloc((size_t)NN * HID * 2);       // 64 MiB
    float*  deg    = (float*)alloc((size_t)NN * 4);
    int*    csroff = (int*)alloc((size_t)(NN + 1) * 4);
    int*    cursor = (int*)alloc((size_t)NN * 4);
    int*    csrsrc = (int*)alloc((size_t)EE * 4);
    float*  p1     = (float*)alloc((size_t)MR * HID * 4);        // 1 MiB
    float*  p2     = (float*)alloc((size_t)MR * HID * 4);        // 1 MiB
    float*  bnsc   = (float*)alloc((size_t)HID * 4);
    float*  bnsh   = (float*)alloc((size_t)HID * 4);
    int*    gstart = (int*)alloc((size_t)(GG + 1) * 4);
    // total ~212 MiB

    // layer-1 concat input [NN,128] in X region (dead before aggbn writes X)
    ushort* Xc128 = X;
    // head scratch in AggX region (dead after layer-3 GEMM; Ybf live till poolbn)
    ushort* hgbf  = AggX;                                     // [128,2048] bf16
    ushort* x1bf  = AggX + (size_t)128 * HID;                 // [128,2048] bf16
    float*  x2f   = (float*)(AggX + (size_t)2 * 128 * HID);   // [128,1024] fp32
    float*  partF = (float*)(AggX + (size_t)3 * 128 * HID);   // 4 MiB fp32 partials

    // ---- CSR build ----
    k_zero_i<<<dim3(NN / 256), dim3(256), 0, stream>>>(cursor, NN);
    k_count<<<dim3(EE / 256), dim3(256), 0, stream>>>(dst, cursor);
    k_scan<<<dim3(1), dim3(1024), 0, stream>>>(cursor, csroff, deg);
    k_zero_i<<<dim3(NN / 256), dim3(256), 0, stream>>>(cursor, NN);
    k_fill<<<dim3(EE / 256), dim3(256), 0, stream>>>(src, dst, csroff, cursor, csrsrc);
    k_gstart<<<dim3(1), dim3(128), 0, stream>>>(graph_id, gstart);

    // ---- layer 1: concat input K=128, single pass ----
    k_h2bf_c<<<dim3(NN * 64 / 256), dim3(256), 0, stream>>>(h, Xc128);
    k_agg_small_c<<<dim3(NN), dim3(64), 0, stream>>>(h, Xc128, csroff, csrsrc, deg);
    k_wt2c<<<dim3(HID / 32, 2, 2), dim3(256), 0, stream>>>(Ws1, Wn1, INF, HID, Wt0, 128);
    k_mgemm<<<dim3(HID / 128, NN / 128, 1), dim3(256), 0, stream>>>(
        Xc128, 128, Wt0, 128, 128,
        (const ushort*)nullptr, 0, (const ushort*)nullptr, 0, 0,
        b1, (float*)nullptr, Ybf, HID, 0, p1, p2, 0);
    k_bn_finalize<<<dim3(HID / 256), dim3(256), 0, stream>>>(p1, p2, g1, be1, bnsc, bnsh);
    k_aggbn<<<dim3(NN), dim3(256), 0, stream>>>(Ybf, bnsc, bnsh, X, AggX, csroff, csrsrc, deg);

    // ---- layer 2: two-pass K=2048+2048 ----
    k_wt2<<<dim3(HID / 32, HID / 32, 2), dim3(256), 0, stream>>>(Ws2, Wn2, HID, HID, Wt0, Wt1, HID);
    k_mgemm<<<dim3(HID / 128, NN / 128, 1), dim3(256), 0, stream>>>(
        X, HID, Wt0, HID, HID,
        AggX, HID, Wt1, HID, HID,
        b2, (float*)nullptr, Ybf, HID, 0, p1, p2, 0);
    k_bn_finalize<<<dim3(HID / 256), dim3(256), 0, stream>>>(p1, p2, g2, be2, bnsc, bnsh);
    k_aggbn<<<dim3(NN), dim3(256), 0, stream>>>(Ybf, bnsc, bnsh, X, AggX, csroff, csrsrc, deg);

    // ---- layer 3 ----
    k_wt2<<<dim3(HID / 32, HID / 32, 2), dim3(256), 0, stream>>>(Ws3, Wn3, HID, HID, Wt0, Wt1, HID);
    k_mgemm<<<dim3(HID / 128, NN / 128, 1), dim3(256), 0, stream>>>(
        X, HID, Wt0, HID, HID,
        AggX, HID, Wt1, HID, HID,
        b3, (float*)nullptr, Ybf, HID, 0, p1, p2, 0);
    k_bn_finalize<<<dim3(HID / 256), dim3(256), 0, stream>>>(p1, p2, g3, be3, bnsc, bnsh);

    // ---- fused BN + pooling (Ybf -> padded bf16 hg; AggX region now scratch) ----
    k_poolbn<<<dim3(HID / 256, 128), dim3(256), 0, stream>>>(Ybf, bnsc, bnsh, gstart, hgbf);

    // ---- MLP head (split-K x4, deterministic two-stage) ----
    k_wt<<<dim3(HID / 32, HID / 32), dim3(256), 0, stream>>>(fc1_w, HID, HID, Wt0, HID);
    k_wt<<<dim3(MID / 32, HID / 32), dim3(256), 0, stream>>>(fc2_w, HID, MID, Wt1, HID);
    k_mgemm<<<dim3(HID / 128, 1, 4), dim3(256), 0, stream>>>(
        hgbf, HID, Wt0, HID, HID / 4,
        (const ushort*)nullptr, 0, (const ushort*)nullptr, 0, 0,
        (const float*)nullptr, partF, (ushort*)nullptr, HID, 0,
        (float*)nullptr, (float*)nullptr, (size_t)128 * HID);
    k_redhead<<<dim3(128 * HID / 256), dim3(256), 0, stream>>>(
        partF, 4, (size_t)128 * HID, fc1_b, HID, x1bf, (float*)nullptr, 128 * HID);
    k_mgemm<<<dim3(MID / 128, 1, 4), dim3(256), 0, stream>>>(
        x1bf, HID, Wt1, HID, HID / 4,
        (const ushort*)nullptr, 0, (const ushort*)nullptr, 0, 0,
        (const float*)nullptr, partF, (ushort*)nullptr, MID, 0,
        (float*)nullptr, (float*)nullptr, (size_t)128 * MID);
    k_redhead<<<dim3(128 * MID / 256), dim3(256), 0, stream>>>(
        partF, 4, (size_t)128 * MID, fc2_b, MID, (ushort*)nullptr, x2f, 128 * MID);
    k_fc3<<<dim3(GG), dim3(256), 0, stream>>>(x2f, fc3_w, fc3_b, out);
}